// Round 1
// baseline (1219.492 us; speedup 1.0000x reference)
//
#include <hip/hip_runtime.h>
#include <hip/hip_bf16.h>

#define N_SAMP 100000
#define MPAD   100096   // 782*128
#define DIM    512
#define NCLS   100
#define NPROT  400
#define KPADC  512

typedef unsigned short ushort_t;
typedef __attribute__((ext_vector_type(8))) short short8;
typedef __attribute__((ext_vector_type(8))) unsigned short ushort8;
typedef __attribute__((ext_vector_type(4))) float f32x4;

__device__ __forceinline__ float b2f(unsigned short u) {
    unsigned int x = ((unsigned int)u) << 16;
    return __builtin_bit_cast(float, x);
}
__device__ __forceinline__ unsigned short f2b(float f) {
    unsigned int x = __builtin_bit_cast(unsigned int, f);
    unsigned int lsb = (x >> 16) & 1u;
    x += 0x7fffu + lsb;
    return (unsigned short)(x >> 16);
}
__device__ __forceinline__ float wred(float v) {
    #pragma unroll
    for (int m = 1; m < 64; m <<= 1) v += __shfl_xor(v, m);
    return v;
}
__device__ __forceinline__ float wmax(float v) {
    #pragma unroll
    for (int m = 1; m < 64; m <<= 1) v = fmaxf(v, __shfl_xor(v, m));
    return v;
}
__device__ __forceinline__ void gload16(const void* g, void* l) {
    __builtin_amdgcn_global_load_lds((const __attribute__((address_space(1))) void*)g,
                                     (__attribute__((address_space(3))) void*)l, 16, 0, 0);
}

// ---------------- conversions ----------------
__global__ void k_cvt_feat(const float* __restrict__ f, ushort_t* __restrict__ o) {
    size_t idx = ((size_t)blockIdx.x * 256 + threadIdx.x) * 8;
    if (idx >= (size_t)MPAD * DIM) return;
    ushort8 r = {0,0,0,0,0,0,0,0};
    if (idx < (size_t)N_SAMP * DIM) {
        f32x4 a = *(const f32x4*)(f + idx);
        f32x4 b = *(const f32x4*)(f + idx + 4);
        #pragma unroll
        for (int j = 0; j < 4; ++j) { r[j] = f2b(a[j]); r[4 + j] = f2b(b[j]); }
    }
    *(ushort8*)(o + idx) = r;
}

__global__ void k_cvt_protos(const float* __restrict__ p, ushort_t* __restrict__ o) {
    size_t idx = ((size_t)blockIdx.x * 256 + threadIdx.x) * 8;
    if (idx >= (size_t)KPADC * DIM) return;
    ushort8 r = {0,0,0,0,0,0,0,0};
    if (idx < (size_t)NPROT * DIM) {
        f32x4 a = *(const f32x4*)(p + idx);
        f32x4 b = *(const f32x4*)(p + idx + 4);
        #pragma unroll
        for (int j = 0; j < 4; ++j) { r[j] = f2b(a[j]); r[4 + j] = f2b(b[j]); }
    }
    *(ushort8*)(o + idx) = r;
}

// ---------------- label bucketing ----------------
__global__ void k_count(const int* __restrict__ labels, int* __restrict__ counts) {
    __shared__ int h[NCLS];
    for (int i = threadIdx.x; i < NCLS; i += blockDim.x) h[i] = 0;
    __syncthreads();
    for (int n = blockIdx.x * blockDim.x + threadIdx.x; n < N_SAMP; n += gridDim.x * blockDim.x)
        atomicAdd(&h[labels[n]], 1);
    __syncthreads();
    for (int i = threadIdx.x; i < NCLS; i += blockDim.x)
        if (h[i]) atomicAdd(&counts[i], h[i]);
}

__global__ void k_scan(const int* __restrict__ counts, int* __restrict__ offsets, int* __restrict__ cursor) {
    if (threadIdx.x == 0) {
        int acc = 0;
        for (int c = 0; c < NCLS; ++c) { offsets[c] = acc; cursor[c] = acc; acc += counts[c]; }
        offsets[NCLS] = acc;
    }
}

__global__ void k_scatter(const int* __restrict__ labels, int* __restrict__ cursor, int* __restrict__ idxlist) {
    int n = blockIdx.x * blockDim.x + threadIdx.x;
    if (n < N_SAMP) {
        int p = atomicAdd(&cursor[labels[n]], 1);
        idxlist[p] = n;
    }
}

// ---------------- GEMM: C[MPAD, 512] = A[MPAD,512] @ B[512,512]^T (bf16 in, bf16 out) ----------------
__global__ __launch_bounds__(256) void k_gemm(const ushort_t* __restrict__ A,
                                              const ushort_t* __restrict__ B,
                                              ushort_t* __restrict__ C) {
    __shared__ ushort_t As[128 * 64];
    __shared__ ushort_t Bs[128 * 64];
    const int bid = blockIdx.x;
    const int nb = bid & 3, mb = bid >> 2;
    const int m0 = mb * 128, n0 = nb * 128;
    const int tid = threadIdx.x;
    const int w = tid >> 6, lane = tid & 63;
    const int wr = w >> 1, wc = w & 1;
    const int l15 = lane & 15, l4 = lane >> 4;

    f32x4 acc[4][4] = {};

    for (int kt = 0; kt < 8; ++kt) {
        const int k0 = kt * 64;
        #pragma unroll
        for (int it = 0; it < 4; ++it) {
            const int seg = w * 4 + it;
            const int li = seg * 64 + lane;
            const int r = li >> 3;
            const int c8 = (li & 7) * 8;
            gload16(A + (size_t)(m0 + r) * DIM + k0 + c8, As + seg * 512);
            gload16(B + (size_t)(n0 + r) * DIM + k0 + c8, Bs + seg * 512);
        }
        asm volatile("s_waitcnt vmcnt(0)" ::: "memory");
        __syncthreads();
        #pragma unroll
        for (int kk = 0; kk < 2; ++kk) {
            short8 af[4], bfr[4];
            #pragma unroll
            for (int mf = 0; mf < 4; ++mf)
                af[mf] = *(const short8*)(As + (wr * 64 + mf * 16 + l15) * 64 + kk * 32 + l4 * 8);
            #pragma unroll
            for (int nf = 0; nf < 4; ++nf)
                bfr[nf] = *(const short8*)(Bs + (wc * 64 + nf * 16 + l15) * 64 + kk * 32 + l4 * 8);
            #pragma unroll
            for (int mf = 0; mf < 4; ++mf)
                #pragma unroll
                for (int nf = 0; nf < 4; ++nf)
                    acc[mf][nf] = __builtin_amdgcn_mfma_f32_16x16x32_bf16(af[mf], bfr[nf], acc[mf][nf], 0, 0, 0);
        }
        __syncthreads();
    }
    #pragma unroll
    for (int mf = 0; mf < 4; ++mf)
        #pragma unroll
        for (int nf = 0; nf < 4; ++nf)
            #pragma unroll
            for (int q = 0; q < 4; ++q) {
                int row = m0 + wr * 64 + mf * 16 + l4 * 4 + q;
                int col = n0 + wc * 64 + nf * 16 + l15;
                C[(size_t)row * KPADC + col] = f2b(acc[mf][nf][q]);
            }
}

// ---------------- Sinkhorn passes ----------------
// FIRST: u_out[k] = sum_n exp(S/eps)           (unweighted)
// else : per row t = sum_k E * r_prev[k], c = 1/(B t); u_out[k] += E * c
template<int FIRST>
__global__ __launch_bounds__(512) void k_sink(const ushort_t* __restrict__ S,
                                              const float* __restrict__ u_prev,
                                              float* __restrict__ u_out) {
    __shared__ float part[8 * 512];
    const int tid = threadIdx.x;
    const int w = tid >> 6, lane = tid & 63;
    const bool lv = lane < 50;   // k = lane*8..lane*8+7 < 400
    float rk[8];
    if (!FIRST) {
        if (lv) {
            f32x4 u0 = *(const f32x4*)(u_prev + lane * 8);
            f32x4 u1 = *(const f32x4*)(u_prev + lane * 8 + 4);
            #pragma unroll
            for (int j = 0; j < 4; ++j) {
                rk[j] = 1.0f / (400.0f * u0[j]);
                rk[4 + j] = 1.0f / (400.0f * u1[j]);
            }
        } else {
            #pragma unroll
            for (int j = 0; j < 8; ++j) rk[j] = 0.0f;
        }
    }
    float racc[8] = {0, 0, 0, 0, 0, 0, 0, 0};
    for (int row = blockIdx.x * 8 + w; row < N_SAMP; row += gridDim.x * 8) {
        short8 v = *(const short8*)(S + (size_t)row * KPADC + lane * 8);
        float e[8];
        #pragma unroll
        for (int j = 0; j < 8; ++j)
            e[j] = lv ? __expf(b2f((unsigned short)v[j]) * 20.0f) : 0.0f;
        if (FIRST) {
            #pragma unroll
            for (int j = 0; j < 8; ++j) racc[j] += e[j];
        } else {
            float t = 0.f;
            #pragma unroll
            for (int j = 0; j < 8; ++j) t += e[j] * rk[j];
            t = wred(t);
            float cn = 1.0f / ((float)N_SAMP * t);
            #pragma unroll
            for (int j = 0; j < 8; ++j) racc[j] += e[j] * cn;
        }
    }
    #pragma unroll
    for (int j = 0; j < 8; ++j) part[w * 512 + lane * 8 + j] = racc[j];
    __syncthreads();
    float s = 0.f;
    #pragma unroll
    for (int w2 = 0; w2 < 8; ++w2) s += part[w2 * 512 + tid];
    if (tid < NPROT) atomicAdd(&u_out[tid], s);
}

// ---------------- phase A finalize: per-sample masked row-normalized weights ----------------
__global__ __launch_bounds__(512) void k_wprime(const ushort_t* __restrict__ S,
                                                const float* __restrict__ u3,
                                                const int* __restrict__ labels,
                                                float* __restrict__ w4) {
    const int tid = threadIdx.x;
    const int w = tid >> 6, lane = tid & 63;
    const int row = blockIdx.x * 8 + w;
    if (row >= N_SAMP) return;
    const bool lv = lane < 50;
    const int lab = labels[row];
    short8 v = *(const short8*)(S + (size_t)row * KPADC + lane * 8);
    float contrib = 0.f, myval = 0.f;
    int myp = -1;
    if (lv) {
        f32x4 u0 = *(const f32x4*)(u3 + lane * 8);
        f32x4 u1 = *(const f32x4*)(u3 + lane * 8 + 4);
        #pragma unroll
        for (int j = 0; j < 8; ++j) {
            int k = lane * 8 + j;
            float uu = (j < 4) ? u0[j] : u1[j - 4];
            float r = 1.0f / (400.0f * uu);
            float e = __expf(b2f((unsigned short)v[j]) * 20.0f);
            int cls = k % 100;
            if (cls == lab) { float val = e * r; contrib += val; myval = val; myp = k / 100; }
        }
    }
    float Sn = wred(contrib);
    if (myp >= 0) w4[(size_t)row * 4 + myp] = myval / Sn;
}

// ---------------- class-bucketed gather: uf[k,:] = sum_n w' f[n,:], colw[k] = sum_n w' ----------------
__global__ __launch_bounds__(128) void k_gather(const int* __restrict__ offsets,
                                                const int* __restrict__ idxlist,
                                                const float* __restrict__ w4,
                                                const ushort_t* __restrict__ fb,
                                                float* __restrict__ uf,
                                                float* __restrict__ colw) {
    const int c = blockIdx.x >> 2;
    const int dc = blockIdx.x & 3;
    const int d = dc * 128 + threadIdx.x;
    const int s = offsets[c], e = offsets[c + 1];
    float a0 = 0, a1 = 0, a2 = 0, a3 = 0, s0 = 0, s1 = 0, s2 = 0, s3 = 0;
    for (int i = s; i < e; ++i) {
        int n = idxlist[i];
        f32x4 wv = *(const f32x4*)(w4 + (size_t)n * 4);
        float f = b2f(fb[(size_t)n * DIM + d]);
        a0 += wv[0] * f; a1 += wv[1] * f; a2 += wv[2] * f; a3 += wv[3] * f;
        s0 += wv[0]; s1 += wv[1]; s2 += wv[2]; s3 += wv[3];
    }
    uf[(size_t)(c)*DIM + d] = a0;
    uf[(size_t)(c + 100) * DIM + d] = a1;
    uf[(size_t)(c + 200) * DIM + d] = a2;
    uf[(size_t)(c + 300) * DIM + d] = a3;
    if (dc == 0 && threadIdx.x == 0) {
        colw[c] = s0; colw[c + 100] = s1; colw[c + 200] = s2; colw[c + 300] = s3;
    }
}

// ---------------- EMA + renorm: protos_new (fp32 + bf16 into padded buffer) ----------------
__global__ __launch_bounds__(64) void k_protonew(const float* __restrict__ protos,
                                                 const float* __restrict__ uf,
                                                 const float* __restrict__ colw,
                                                 float* __restrict__ pn,
                                                 ushort_t* __restrict__ pb) {
    const int k = blockIdx.x;     // 0..399
    const int lane = threadIdx.x; // 0..63
    const float cw = fmaxf(colw[k], 1e-12f);
    float v[8]; float nn = 0.f;
    #pragma unroll
    for (int j = 0; j < 8; ++j) {
        int d = lane * 8 + j;
        float x = 0.99f * protos[(size_t)k * DIM + d] + 0.01f * (uf[(size_t)k * DIM + d] / cw);
        v[j] = x; nn += x * x;
    }
    nn = wred(nn);
    float inv = 1.0f / fmaxf(sqrtf(nn), 1e-12f);
    #pragma unroll
    for (int j = 0; j < 8; ++j) {
        int d = lane * 8 + j;
        float x = v[j] * inv;
        pn[(size_t)k * DIM + d] = x;
        pb[(size_t)k * DIM + d] = f2b(x);
    }
}

// ---------------- proto-contrast: accumulate sum_i (ppos_i - pneg_i) ----------------
__global__ __launch_bounds__(256) void k_pcon(const float* __restrict__ pn, float* __restrict__ pacc) {
    __shared__ float pi[512];
    __shared__ float g[NPROT];
    __shared__ float rmx[4], rse[4], rsp[4];
    const int i = blockIdx.x;
    const int tid = threadIdx.x;
    const int w = tid >> 6, lane = tid & 63;
    for (int d = tid; d < 512; d += 256) pi[d] = pn[(size_t)i * DIM + d];
    __syncthreads();
    for (int j = w; j < NPROT; j += 4) {
        const float* pj = pn + (size_t)j * DIM;
        f32x4 p0 = *(const f32x4*)(pj + lane * 8);
        f32x4 p1 = *(const f32x4*)(pj + lane * 8 + 4);
        float dot = 0.f;
        #pragma unroll
        for (int jj = 0; jj < 4; ++jj) {
            dot += pi[lane * 8 + jj] * p0[jj];
            dot += pi[lane * 8 + 4 + jj] * p1[jj];
        }
        dot = wred(dot);
        if (lane == 0) g[j] = dot * 2.0f;   // /0.5
    }
    __syncthreads();
    float mx = -1e30f;
    for (int j = tid; j < NPROT; j += 256) mx = fmaxf(mx, g[j]);
    mx = wmax(mx);
    if (lane == 0) rmx[w] = mx;
    __syncthreads();
    mx = fmaxf(fmaxf(rmx[0], rmx[1]), fmaxf(rmx[2], rmx[3]));
    const int ci = i % 100;
    float se = 0.f, sp = 0.f;
    for (int j = tid; j < NPROT; j += 256) {
        if (j == i) continue;
        float lg = g[j] - mx;
        se += __expf(lg);
        if (j % 100 == ci) sp += lg;
    }
    se = wred(se); sp = wred(sp);
    if (lane == 0) { rse[w] = se; rsp[w] = sp; }
    __syncthreads();
    if (tid == 0) {
        float SE = rse[0] + rse[1] + rse[2] + rse[3];
        float SP = rsp[0] + rsp[1] + rsp[2] + rsp[3];
        atomicAdd(pacc, SP * (1.0f / 3.0f) - logf(SE));
    }
}

// ---------------- phase B finalize: out[n] = neg - pos + pcon ----------------
__global__ __launch_bounds__(512) void k_final(const ushort_t* __restrict__ S,
                                               const float* __restrict__ u3,
                                               const int* __restrict__ labels,
                                               const float* __restrict__ pacc,
                                               float* __restrict__ out) {
    const int tid = threadIdx.x;
    const int w = tid >> 6, lane = tid & 63;
    const int row = blockIdx.x * 8 + w;
    if (row >= N_SAMP) return;
    const bool lv = lane < 50;
    const int lab = labels[row];
    short8 v = *(const short8*)(S + (size_t)row * KPADC + lane * 8);
    float sw = 0.f, swl = 0.f, sexp = 0.f;
    if (lv) {
        f32x4 u0 = *(const f32x4*)(u3 + lane * 8);
        f32x4 u1 = *(const f32x4*)(u3 + lane * 8 + 4);
        #pragma unroll
        for (int j = 0; j < 8; ++j) {
            int k = lane * 8 + j;
            float s = b2f((unsigned short)v[j]);
            float e = __expf(s * 20.0f);           // exp(s/EPS)
            float uu = (j < 4) ? u0[j] : u1[j - 4];
            float r = 1.0f / (400.0f * uu);
            float lgt = s * 10.0f;                 // s/TEMP
            sexp += sqrtf(e);                      // exp(10 s)
            int cls = k % 100;
            if (cls == lab) { sw += e * r; swl += e * r * lgt; }
        }
    }
    sw = wred(sw); swl = wred(swl); sexp = wred(sexp);
    if (lane == 0) {
        float pos = swl / sw;
        float neg = logf(sexp);
        out[row] = (neg - pos) - pacc[0] * (1.0f / 400.0f);
    }
}

extern "C" void kernel_launch(void* const* d_in, const int* in_sizes, int n_in,
                              void* d_out, int out_size, void* d_ws, size_t ws_size,
                              hipStream_t stream) {
    const float* features = (const float*)d_in[0];
    const float* protos   = (const float*)d_in[1];
    const int*   labels   = (const int*)d_in[2];
    float* out = (float*)d_out;

    char* ws = (char*)d_ws;
    size_t off = 0;
    auto alloc = [&](size_t bytes) -> char* {
        char* p = ws + off;
        off += (bytes + 255) & ~(size_t)255;
        return p;
    };
    ushort_t* fbf16 = (ushort_t*)alloc((size_t)MPAD * DIM * 2);
    ushort_t* Sbuf  = (ushort_t*)alloc((size_t)MPAD * DIM * 2);
    ushort_t* pbf16 = (ushort_t*)alloc((size_t)KPADC * DIM * 2);
    float* w4   = (float*)alloc((size_t)N_SAMP * 4 * 4);
    float* uf   = (float*)alloc((size_t)NPROT * DIM * 4);
    float* pnf  = (float*)alloc((size_t)NPROT * DIM * 4);
    float* zreg = (float*)alloc(16384);  // zeroed region
    float* uA1 = zreg;          float* uA2 = zreg + 512;  float* uA3 = zreg + 1024;
    float* uB1 = zreg + 1536;   float* uB2 = zreg + 2048; float* uB3 = zreg + 2560;
    float* pacc = zreg + 3072;
    int* counts = (int*)(zreg + 3080);
    int* offsets = (int*)alloc(101 * 4);
    int* cursor  = (int*)alloc(100 * 4);
    float* colw  = (float*)alloc(NPROT * 4);
    int* idxlist = (int*)alloc((size_t)N_SAMP * 4);
    if (off > ws_size) return;  // visible failure instead of corruption

    hipMemsetAsync(zreg, 0, 16384, stream);

    k_cvt_feat<<<25024, 256, 0, stream>>>(features, fbf16);
    k_cvt_protos<<<128, 256, 0, stream>>>(protos, pbf16);
    k_count<<<256, 256, 0, stream>>>(labels, counts);
    k_scan<<<1, 64, 0, stream>>>(counts, offsets, cursor);
    k_scatter<<<(N_SAMP + 255) / 256, 256, 0, stream>>>(labels, cursor, idxlist);

    // ---- phase A ----
    k_gemm<<<(MPAD / 128) * 4, 256, 0, stream>>>(fbf16, pbf16, Sbuf);
    k_sink<1><<<512, 512, 0, stream>>>(Sbuf, nullptr, uA1);
    k_sink<0><<<512, 512, 0, stream>>>(Sbuf, uA1, uA2);
    k_sink<0><<<512, 512, 0, stream>>>(Sbuf, uA2, uA3);
    k_wprime<<<12500, 512, 0, stream>>>(Sbuf, uA3, labels, w4);
    k_gather<<<400, 128, 0, stream>>>(offsets, idxlist, w4, fbf16, uf, colw);
    k_protonew<<<400, 64, 0, stream>>>(protos, uf, colw, pnf, pbf16);
    k_pcon<<<400, 256, 0, stream>>>(pnf, pacc);

    // ---- phase B ----
    k_gemm<<<(MPAD / 128) * 4, 256, 0, stream>>>(fbf16, pbf16, Sbuf);
    k_sink<1><<<512, 512, 0, stream>>>(Sbuf, nullptr, uB1);
    k_sink<0><<<512, 512, 0, stream>>>(Sbuf, uB1, uB2);
    k_sink<0><<<512, 512, 0, stream>>>(Sbuf, uB2, uB3);
    k_final<<<12500, 512, 0, stream>>>(Sbuf, uB3, labels, pacc, out);
}

// Round 2
// 951.711 us; speedup vs baseline: 1.2814x; 1.2814x over previous
//
#include <hip/hip_runtime.h>
#include <hip/hip_bf16.h>

#define N_SAMP 100000
#define MPAD   100096   // 782*128
#define DIM    512
#define NCLS   100
#define NPROT  400
#define SLD    400      // S row stride (bf16 elements); 800 B rows stay 16B-aligned
#define GCHUNK 16       // sample-chunks per class in gather

typedef unsigned short ushort_t;
typedef __attribute__((ext_vector_type(8))) short short8;
typedef __attribute__((ext_vector_type(8))) unsigned short ushort8;
typedef __attribute__((ext_vector_type(4))) float f32x4;

__device__ __forceinline__ float b2f(unsigned short u) {
    unsigned int x = ((unsigned int)u) << 16;
    return __builtin_bit_cast(float, x);
}
__device__ __forceinline__ unsigned short f2b(float f) {
    unsigned int x = __builtin_bit_cast(unsigned int, f);
    unsigned int lsb = (x >> 16) & 1u;
    x += 0x7fffu + lsb;
    return (unsigned short)(x >> 16);
}
__device__ __forceinline__ float wred(float v) {
    #pragma unroll
    for (int m = 1; m < 64; m <<= 1) v += __shfl_xor(v, m);
    return v;
}
__device__ __forceinline__ float wmax(float v) {
    #pragma unroll
    for (int m = 1; m < 64; m <<= 1) v = fmaxf(v, __shfl_xor(v, m));
    return v;
}
__device__ __forceinline__ void gload16(const void* g, void* l) {
    __builtin_amdgcn_global_load_lds((const __attribute__((address_space(1))) void*)g,
                                     (__attribute__((address_space(3))) void*)l, 16, 0, 0);
}

// ---------------- conversions ----------------
__global__ void k_cvt_feat(const float* __restrict__ f, ushort_t* __restrict__ o) {
    size_t idx = ((size_t)blockIdx.x * 256 + threadIdx.x) * 8;
    if (idx >= (size_t)MPAD * DIM) return;
    ushort8 r = {0,0,0,0,0,0,0,0};
    if (idx < (size_t)N_SAMP * DIM) {
        f32x4 a = *(const f32x4*)(f + idx);
        f32x4 b = *(const f32x4*)(f + idx + 4);
        #pragma unroll
        for (int j = 0; j < 4; ++j) { r[j] = f2b(a[j]); r[4 + j] = f2b(b[j]); }
    }
    *(ushort8*)(o + idx) = r;
}

__global__ void k_cvt_protos(const float* __restrict__ p, ushort_t* __restrict__ o) {
    size_t idx = ((size_t)blockIdx.x * 256 + threadIdx.x) * 8;
    if (idx >= (size_t)DIM * DIM) return;
    ushort8 r = {0,0,0,0,0,0,0,0};
    if (idx < (size_t)NPROT * DIM) {
        f32x4 a = *(const f32x4*)(p + idx);
        f32x4 b = *(const f32x4*)(p + idx + 4);
        #pragma unroll
        for (int j = 0; j < 4; ++j) { r[j] = f2b(a[j]); r[4 + j] = f2b(b[j]); }
    }
    *(ushort8*)(o + idx) = r;
}

// ---------------- label bucketing ----------------
__global__ void k_count(const int* __restrict__ labels, int* __restrict__ counts) {
    __shared__ int h[NCLS];
    for (int i = threadIdx.x; i < NCLS; i += blockDim.x) h[i] = 0;
    __syncthreads();
    for (int n = blockIdx.x * blockDim.x + threadIdx.x; n < N_SAMP; n += gridDim.x * blockDim.x)
        atomicAdd(&h[labels[n]], 1);
    __syncthreads();
    for (int i = threadIdx.x; i < NCLS; i += blockDim.x)
        if (h[i]) atomicAdd(&counts[i], h[i]);
}

__global__ void k_scan(const int* __restrict__ counts, int* __restrict__ offsets, int* __restrict__ cursor) {
    if (threadIdx.x == 0) {
        int acc = 0;
        for (int c = 0; c < NCLS; ++c) { offsets[c] = acc; cursor[c] = acc; acc += counts[c]; }
        offsets[NCLS] = acc;
    }
}

__global__ void k_scatter(const int* __restrict__ labels, int* __restrict__ cursor, int* __restrict__ idxlist) {
    int n = blockIdx.x * blockDim.x + threadIdx.x;
    if (n < N_SAMP) {
        int p = atomicAdd(&cursor[labels[n]], 1);
        idxlist[p] = n;
    }
}

// ---------------- GEMM: C[MPAD, 400(+pad)] = A[MPAD,512] @ B[512,512]^T (bf16 in, bf16 out) ----------------
__global__ __launch_bounds__(256) void k_gemm(const ushort_t* __restrict__ A,
                                              const ushort_t* __restrict__ B,
                                              ushort_t* __restrict__ C) {
    __shared__ ushort_t As[128 * 64];
    __shared__ ushort_t Bs[128 * 64];
    const int bid = blockIdx.x;
    const int nb = bid & 3, mb = bid >> 2;
    const int m0 = mb * 128, n0 = nb * 128;
    const int tid = threadIdx.x;
    const int w = tid >> 6, lane = tid & 63;
    const int wr = w >> 1, wc = w & 1;
    const int l15 = lane & 15, l4 = lane >> 4;

    f32x4 acc[4][4] = {};

    for (int kt = 0; kt < 8; ++kt) {
        const int k0 = kt * 64;
        #pragma unroll
        for (int it = 0; it < 4; ++it) {
            const int seg = w * 4 + it;
            const int li = seg * 64 + lane;
            const int r = li >> 3;
            const int c8 = (li & 7) * 8;
            gload16(A + (size_t)(m0 + r) * DIM + k0 + c8, As + seg * 512);
            gload16(B + (size_t)(n0 + r) * DIM + k0 + c8, Bs + seg * 512);
        }
        asm volatile("s_waitcnt vmcnt(0)" ::: "memory");
        __syncthreads();
        #pragma unroll
        for (int kk = 0; kk < 2; ++kk) {
            short8 af[4], bfr[4];
            #pragma unroll
            for (int mf = 0; mf < 4; ++mf)
                af[mf] = *(const short8*)(As + (wr * 64 + mf * 16 + l15) * 64 + kk * 32 + l4 * 8);
            #pragma unroll
            for (int nf = 0; nf < 4; ++nf)
                bfr[nf] = *(const short8*)(Bs + (wc * 64 + nf * 16 + l15) * 64 + kk * 32 + l4 * 8);
            #pragma unroll
            for (int mf = 0; mf < 4; ++mf)
                #pragma unroll
                for (int nf = 0; nf < 4; ++nf)
                    acc[mf][nf] = __builtin_amdgcn_mfma_f32_16x16x32_bf16(af[mf], bfr[nf], acc[mf][nf], 0, 0, 0);
        }
        __syncthreads();
    }
    #pragma unroll
    for (int mf = 0; mf < 4; ++mf)
        #pragma unroll
        for (int nf = 0; nf < 4; ++nf) {
            int col = n0 + wc * 64 + nf * 16 + l15;
            if (col < NPROT) {
                #pragma unroll
                for (int q = 0; q < 4; ++q) {
                    int row = m0 + wr * 64 + mf * 16 + l4 * 4 + q;
                    C[(size_t)row * SLD + col] = f2b(acc[mf][nf][q]);
                }
            }
        }
}

// ---------------- Sinkhorn passes ----------------
template<int FIRST>
__global__ __launch_bounds__(512) void k_sink(const ushort_t* __restrict__ S,
                                              const float* __restrict__ u_prev,
                                              float* __restrict__ u_out) {
    __shared__ float part[8 * 512];
    const int tid = threadIdx.x;
    const int w = tid >> 6, lane = tid & 63;
    const bool lv = lane < 50;   // k = lane*8..lane*8+7 < 400
    float rk[8];
    if (!FIRST) {
        if (lv) {
            f32x4 u0 = *(const f32x4*)(u_prev + lane * 8);
            f32x4 u1 = *(const f32x4*)(u_prev + lane * 8 + 4);
            #pragma unroll
            for (int j = 0; j < 4; ++j) {
                rk[j] = 1.0f / (400.0f * u0[j]);
                rk[4 + j] = 1.0f / (400.0f * u1[j]);
            }
        } else {
            #pragma unroll
            for (int j = 0; j < 8; ++j) rk[j] = 0.0f;
        }
    }
    float racc[8] = {0, 0, 0, 0, 0, 0, 0, 0};
    for (int row = blockIdx.x * 8 + w; row < N_SAMP; row += gridDim.x * 8) {
        short8 v = *(const short8*)(S + (size_t)row * SLD + lane * 8);
        float e[8];
        #pragma unroll
        for (int j = 0; j < 8; ++j)
            e[j] = lv ? __expf(b2f((unsigned short)v[j]) * 20.0f) : 0.0f;
        if (FIRST) {
            #pragma unroll
            for (int j = 0; j < 8; ++j) racc[j] += e[j];
        } else {
            float t = 0.f;
            #pragma unroll
            for (int j = 0; j < 8; ++j) t += e[j] * rk[j];
            t = wred(t);
            float cn = 1.0f / ((float)N_SAMP * t);
            #pragma unroll
            for (int j = 0; j < 8; ++j) racc[j] += e[j] * cn;
        }
    }
    #pragma unroll
    for (int j = 0; j < 8; ++j) part[w * 512 + lane * 8 + j] = racc[j];
    __syncthreads();
    float s = 0.f;
    #pragma unroll
    for (int w2 = 0; w2 < 8; ++w2) s += part[w2 * 512 + tid];
    if (tid < NPROT) atomicAdd(&u_out[tid], s);
}

// ---------------- phase A finalize: per-sample masked row-normalized weights ----------------
__global__ __launch_bounds__(512) void k_wprime(const ushort_t* __restrict__ S,
                                                const float* __restrict__ u3,
                                                const int* __restrict__ labels,
                                                float* __restrict__ w4) {
    const int tid = threadIdx.x;
    const int w = tid >> 6, lane = tid & 63;
    const int row = blockIdx.x * 8 + w;
    if (row >= N_SAMP) return;
    const bool lv = lane < 50;
    const int lab = labels[row];
    short8 v = *(const short8*)(S + (size_t)row * SLD + lane * 8);
    float contrib = 0.f, myval = 0.f;
    int myp = -1;
    if (lv) {
        f32x4 u0 = *(const f32x4*)(u3 + lane * 8);
        f32x4 u1 = *(const f32x4*)(u3 + lane * 8 + 4);
        #pragma unroll
        for (int j = 0; j < 8; ++j) {
            int k = lane * 8 + j;
            float uu = (j < 4) ? u0[j] : u1[j - 4];
            float r = 1.0f / (400.0f * uu);
            float e = __expf(b2f((unsigned short)v[j]) * 20.0f);
            int cls = k % 100;
            if (cls == lab) { float val = e * r; contrib += val; myval = val; myp = k / 100; }
        }
    }
    float Sn = wred(contrib);
    if (myp >= 0) w4[(size_t)row * 4 + myp] = myval / Sn;
}

// ---------------- class-bucketed gather (parallel over sample-chunks) ----------------
// grid: NCLS * 4 dchunks * GCHUNK sample-chunks; atomic accumulation into uf/colw
__global__ __launch_bounds__(128) void k_gather(const int* __restrict__ offsets,
                                                const int* __restrict__ idxlist,
                                                const float* __restrict__ w4,
                                                const ushort_t* __restrict__ fb,
                                                float* __restrict__ uf,
                                                float* __restrict__ colw) {
    const int c  = blockIdx.x / (4 * GCHUNK);
    const int rr = blockIdx.x % (4 * GCHUNK);
    const int dc = rr / GCHUNK;
    const int sc = rr % GCHUNK;
    const int d = dc * 128 + threadIdx.x;
    const int s = offsets[c], e = offsets[c + 1];
    const int cnt = e - s;
    const int per = (cnt + GCHUNK - 1) / GCHUNK;
    const int i0 = s + sc * per;
    const int i1 = min(e, i0 + per);
    if (i0 >= i1) return;
    float a0 = 0, a1 = 0, a2 = 0, a3 = 0, s0 = 0, s1 = 0, s2 = 0, s3 = 0;
    for (int i = i0; i < i1; ++i) {
        int n = idxlist[i];
        f32x4 wv = *(const f32x4*)(w4 + (size_t)n * 4);
        float f = b2f(fb[(size_t)n * DIM + d]);
        a0 += wv[0] * f; a1 += wv[1] * f; a2 += wv[2] * f; a3 += wv[3] * f;
        s0 += wv[0]; s1 += wv[1]; s2 += wv[2]; s3 += wv[3];
    }
    atomicAdd(&uf[(size_t)(c)       * DIM + d], a0);
    atomicAdd(&uf[(size_t)(c + 100) * DIM + d], a1);
    atomicAdd(&uf[(size_t)(c + 200) * DIM + d], a2);
    atomicAdd(&uf[(size_t)(c + 300) * DIM + d], a3);
    if (dc == 0 && threadIdx.x == 0) {
        atomicAdd(&colw[c], s0);
        atomicAdd(&colw[c + 100], s1);
        atomicAdd(&colw[c + 200], s2);
        atomicAdd(&colw[c + 300], s3);
    }
}

// ---------------- EMA + renorm: protos_new (fp32 + bf16) ----------------
__global__ __launch_bounds__(64) void k_protonew(const float* __restrict__ protos,
                                                 const float* __restrict__ uf,
                                                 const float* __restrict__ colw,
                                                 float* __restrict__ pn,
                                                 ushort_t* __restrict__ pb) {
    const int k = blockIdx.x;     // 0..399
    const int lane = threadIdx.x; // 0..63
    const float cw = fmaxf(colw[k], 1e-12f);
    float v[8]; float nn = 0.f;
    #pragma unroll
    for (int j = 0; j < 8; ++j) {
        int d = lane * 8 + j;
        float x = 0.99f * protos[(size_t)k * DIM + d] + 0.01f * (uf[(size_t)k * DIM + d] / cw);
        v[j] = x; nn += x * x;
    }
    nn = wred(nn);
    float inv = 1.0f / fmaxf(sqrtf(nn), 1e-12f);
    #pragma unroll
    for (int j = 0; j < 8; ++j) {
        int d = lane * 8 + j;
        float x = v[j] * inv;
        pn[(size_t)k * DIM + d] = x;
        pb[(size_t)k * DIM + d] = f2b(x);
    }
}

// ---------------- proto-contrast ----------------
__global__ __launch_bounds__(256) void k_pcon(const float* __restrict__ pn, float* __restrict__ pacc) {
    __shared__ float pi[512];
    __shared__ float g[NPROT];
    __shared__ float rmx[4], rse[4], rsp[4];
    const int i = blockIdx.x;
    const int tid = threadIdx.x;
    const int w = tid >> 6, lane = tid & 63;
    for (int d = tid; d < 512; d += 256) pi[d] = pn[(size_t)i * DIM + d];
    __syncthreads();
    for (int j = w; j < NPROT; j += 4) {
        const float* pj = pn + (size_t)j * DIM;
        f32x4 p0 = *(const f32x4*)(pj + lane * 8);
        f32x4 p1 = *(const f32x4*)(pj + lane * 8 + 4);
        float dot = 0.f;
        #pragma unroll
        for (int jj = 0; jj < 4; ++jj) {
            dot += pi[lane * 8 + jj] * p0[jj];
            dot += pi[lane * 8 + 4 + jj] * p1[jj];
        }
        dot = wred(dot);
        if (lane == 0) g[j] = dot * 2.0f;   // /0.5
    }
    __syncthreads();
    float mx = -1e30f;
    for (int j = tid; j < NPROT; j += 256) mx = fmaxf(mx, g[j]);
    mx = wmax(mx);
    if (lane == 0) rmx[w] = mx;
    __syncthreads();
    mx = fmaxf(fmaxf(rmx[0], rmx[1]), fmaxf(rmx[2], rmx[3]));
    const int ci = i % 100;
    float se = 0.f, sp = 0.f;
    for (int j = tid; j < NPROT; j += 256) {
        if (j == i) continue;
        float lg = g[j] - mx;
        se += __expf(lg);
        if (j % 100 == ci) sp += lg;
    }
    se = wred(se); sp = wred(sp);
    if (lane == 0) { rse[w] = se; rsp[w] = sp; }
    __syncthreads();
    if (tid == 0) {
        float SE = rse[0] + rse[1] + rse[2] + rse[3];
        float SP = rsp[0] + rsp[1] + rsp[2] + rsp[3];
        atomicAdd(pacc, SP * (1.0f / 3.0f) - logf(SE));
    }
}

// ---------------- phase B finalize ----------------
__global__ __launch_bounds__(512) void k_final(const ushort_t* __restrict__ S,
                                               const float* __restrict__ u3,
                                               const int* __restrict__ labels,
                                               const float* __restrict__ pacc,
                                               float* __restrict__ out) {
    const int tid = threadIdx.x;
    const int w = tid >> 6, lane = tid & 63;
    const int row = blockIdx.x * 8 + w;
    if (row >= N_SAMP) return;
    const bool lv = lane < 50;
    const int lab = labels[row];
    short8 v = *(const short8*)(S + (size_t)row * SLD + lane * 8);
    float sw = 0.f, swl = 0.f, sexp = 0.f;
    if (lv) {
        f32x4 u0 = *(const f32x4*)(u3 + lane * 8);
        f32x4 u1 = *(const f32x4*)(u3 + lane * 8 + 4);
        #pragma unroll
        for (int j = 0; j < 8; ++j) {
            int k = lane * 8 + j;
            float s = b2f((unsigned short)v[j]);
            float e = __expf(s * 20.0f);           // exp(s/EPS)
            float uu = (j < 4) ? u0[j] : u1[j - 4];
            float r = 1.0f / (400.0f * uu);
            float lgt = s * 10.0f;                 // s/TEMP
            sexp += sqrtf(e);                      // exp(10 s)
            int cls = k % 100;
            if (cls == lab) { sw += e * r; swl += e * r * lgt; }
        }
    }
    sw = wred(sw); swl = wred(swl); sexp = wred(sexp);
    if (lane == 0) {
        float pos = swl / sw;
        float neg = logf(sexp);
        out[row] = (neg - pos) - pacc[0] * (1.0f / 400.0f);
    }
}

extern "C" void kernel_launch(void* const* d_in, const int* in_sizes, int n_in,
                              void* d_out, int out_size, void* d_ws, size_t ws_size,
                              hipStream_t stream) {
    const float* features = (const float*)d_in[0];
    const float* protos   = (const float*)d_in[1];
    const int*   labels   = (const int*)d_in[2];
    float* out = (float*)d_out;

    char* ws = (char*)d_ws;
    size_t off = 0;
    auto alloc = [&](size_t bytes) -> char* {
        char* p = ws + off;
        off += (bytes + 255) & ~(size_t)255;
        return p;
    };
    ushort_t* fbf16 = (ushort_t*)alloc((size_t)MPAD * DIM * 2);
    ushort_t* Sbuf  = (ushort_t*)alloc((size_t)MPAD * SLD * 2);
    ushort_t* pbf16 = (ushort_t*)alloc((size_t)DIM * DIM * 2);
    float* w4   = (float*)alloc((size_t)N_SAMP * 4 * 4);
    float* uf   = (float*)alloc((size_t)NPROT * DIM * 4);
    float* pnf  = (float*)alloc((size_t)NPROT * DIM * 4);
    float* zreg = (float*)alloc(16384);  // zeroed region
    float* uA1 = zreg;          float* uA2 = zreg + 512;  float* uA3 = zreg + 1024;
    float* uB1 = zreg + 1536;   float* uB2 = zreg + 2048; float* uB3 = zreg + 2560;
    float* pacc = zreg + 3072;
    int* counts = (int*)(zreg + 3080);
    float* colw = zreg + 3200;           // 400 floats, zeroed
    int* offsets = (int*)alloc(101 * 4);
    int* cursor  = (int*)alloc(100 * 4);
    int* idxlist = (int*)alloc((size_t)N_SAMP * 4);
    if (off > ws_size) return;  // visible failure instead of corruption

    hipMemsetAsync(zreg, 0, 16384, stream);
    hipMemsetAsync(uf, 0, (size_t)NPROT * DIM * 4, stream);

    k_cvt_feat<<<25024, 256, 0, stream>>>(features, fbf16);
    k_cvt_protos<<<128, 256, 0, stream>>>(protos, pbf16);
    k_count<<<256, 256, 0, stream>>>(labels, counts);
    k_scan<<<1, 64, 0, stream>>>(counts, offsets, cursor);
    k_scatter<<<(N_SAMP + 255) / 256, 256, 0, stream>>>(labels, cursor, idxlist);

    // ---- phase A ----
    k_gemm<<<(MPAD / 128) * 4, 256, 0, stream>>>(fbf16, pbf16, Sbuf);
    k_sink<1><<<512, 512, 0, stream>>>(Sbuf, nullptr, uA1);
    k_sink<0><<<512, 512, 0, stream>>>(Sbuf, uA1, uA2);
    k_sink<0><<<512, 512, 0, stream>>>(Sbuf, uA2, uA3);
    k_wprime<<<12500, 512, 0, stream>>>(Sbuf, uA3, labels, w4);
    k_gather<<<NCLS * 4 * GCHUNK, 128, 0, stream>>>(offsets, idxlist, w4, fbf16, uf, colw);
    k_protonew<<<400, 64, 0, stream>>>(protos, uf, colw, pnf, pbf16);
    k_pcon<<<400, 256, 0, stream>>>(pnf, pacc);

    // ---- phase B ----
    k_gemm<<<(MPAD / 128) * 4, 256, 0, stream>>>(fbf16, pbf16, Sbuf);
    k_sink<1><<<512, 512, 0, stream>>>(Sbuf, nullptr, uB1);
    k_sink<0><<<512, 512, 0, stream>>>(Sbuf, uB1, uB2);
    k_sink<0><<<512, 512, 0, stream>>>(Sbuf, uB2, uB3);
    k_final<<<12500, 512, 0, stream>>>(Sbuf, uB3, labels, pacc, out);
}

// Round 3
// 895.828 us; speedup vs baseline: 1.3613x; 1.0624x over previous
//
#include <hip/hip_runtime.h>
#include <hip/hip_bf16.h>

#define N_SAMP 100000
#define MPAD   100096   // 782*128
#define DIM    512
#define NCLS   100
#define NPROT  400
#define SLD    400      // S row stride (bf16 elements); 800 B rows, 16B-aligned
#define GCHUNK 16       // sample-chunks per class in gather
#define MB_CNT 782      // MPAD/128

typedef unsigned short ushort_t;
typedef __attribute__((ext_vector_type(8))) short short8;
typedef __attribute__((ext_vector_type(8))) unsigned short ushort8;
typedef __attribute__((ext_vector_type(4))) float f32x4;

__device__ __forceinline__ float b2f(unsigned short u) {
    unsigned int x = ((unsigned int)u) << 16;
    return __builtin_bit_cast(float, x);
}
__device__ __forceinline__ unsigned short f2b(float f) {
    unsigned int x = __builtin_bit_cast(unsigned int, f);
    unsigned int lsb = (x >> 16) & 1u;
    x += 0x7fffu + lsb;
    return (unsigned short)(x >> 16);
}
__device__ __forceinline__ float wred(float v) {
    #pragma unroll
    for (int m = 1; m < 64; m <<= 1) v += __shfl_xor(v, m);
    return v;
}
__device__ __forceinline__ float wmax(float v) {
    #pragma unroll
    for (int m = 1; m < 64; m <<= 1) v = fmaxf(v, __shfl_xor(v, m));
    return v;
}
__device__ __forceinline__ void gload16(const void* g, void* l) {
    __builtin_amdgcn_global_load_lds((const __attribute__((address_space(1))) void*)g,
                                     (__attribute__((address_space(3))) void*)l, 16, 0, 0);
}

// ---------------- fused prep: cvt feat + cvt protos + label count ----------------
// blocks [0,25024): feat cvt; [25024,25152): proto cvt; [25152,25216): count
__global__ void k_prep(const float* __restrict__ f, const float* __restrict__ p,
                       const int* __restrict__ labels,
                       ushort_t* __restrict__ fb, ushort_t* __restrict__ pb,
                       int* __restrict__ counts) {
    __shared__ int h[NCLS];
    const int b = blockIdx.x;
    if (b < 25024) {
        size_t idx = ((size_t)b * 256 + threadIdx.x) * 8;
        ushort8 r = {0,0,0,0,0,0,0,0};
        if (idx < (size_t)N_SAMP * DIM) {
            f32x4 a = *(const f32x4*)(f + idx);
            f32x4 c = *(const f32x4*)(f + idx + 4);
            #pragma unroll
            for (int j = 0; j < 4; ++j) { r[j] = f2b(a[j]); r[4 + j] = f2b(c[j]); }
        }
        *(ushort8*)(fb + idx) = r;
    } else if (b < 25152) {
        size_t idx = ((size_t)(b - 25024) * 256 + threadIdx.x) * 8;
        ushort8 r = {0,0,0,0,0,0,0,0};
        if (idx < (size_t)NPROT * DIM) {
            f32x4 a = *(const f32x4*)(p + idx);
            f32x4 c = *(const f32x4*)(p + idx + 4);
            #pragma unroll
            for (int j = 0; j < 4; ++j) { r[j] = f2b(a[j]); r[4 + j] = f2b(c[j]); }
        }
        *(ushort8*)(pb + idx) = r;
    } else {
        for (int i = threadIdx.x; i < NCLS; i += 256) h[i] = 0;
        __syncthreads();
        const int step = 64 * 256;
        for (int n = (b - 25152) * 256 + threadIdx.x; n < N_SAMP; n += step)
            atomicAdd(&h[labels[n]], 1);
        __syncthreads();
        for (int i = threadIdx.x; i < NCLS; i += 256)
            if (h[i]) atomicAdd(&counts[i], h[i]);
    }
}

// ---------------- parallel prefix scan over 100 class counts ----------------
__global__ void k_scan(const int* __restrict__ counts, int* __restrict__ offsets,
                       int* __restrict__ cursor) {
    __shared__ int c[NCLS];
    const int t = threadIdx.x;
    if (t < NCLS) c[t] = counts[t];
    __syncthreads();
    if (t <= NCLS) {
        int acc = 0;
        for (int i = 0; i < t && i < NCLS; ++i) acc += c[i];
        offsets[t] = acc;
        if (t < NCLS) cursor[t] = acc;
    }
}

__global__ void k_scatter(const int* __restrict__ labels, int* __restrict__ cursor,
                          int* __restrict__ idxlist) {
    int n = blockIdx.x * blockDim.x + threadIdx.x;
    if (n < N_SAMP) {
        int p = atomicAdd(&cursor[labels[n]], 1);
        idxlist[p] = n;
    }
}

// ---------------- GEMM + fused sink pass 1 ----------------
// C[MPAD,400(+pad)] = A[MPAD,512] @ B[512,512]^T, bf16; u1[k] += sum_rows exp(C*20)
// XCD-swizzled grid: 8*98*4 blocks; 4 nb-siblings of each mb co-located on one XCD.
__global__ __launch_bounds__(256) void k_gemm(const ushort_t* __restrict__ A,
                                              const ushort_t* __restrict__ B,
                                              ushort_t* __restrict__ C,
                                              float* __restrict__ u1) {
    __shared__ ushort_t As[128 * 64];
    __shared__ ushort_t Bs[128 * 64];
    __shared__ float cs[128];
    const int pidx = blockIdx.x;
    const int x = pidx & 7, sl = pidx >> 3;
    const int mb = (sl >> 2) * 8 + x;
    const int nb = sl & 3;
    if (mb >= MB_CNT) return;        // uniform early-out, before any barrier
    const int m0 = mb * 128, n0 = nb * 128;
    const int tid = threadIdx.x;
    const int w = tid >> 6, lane = tid & 63;
    const int wr = w >> 1, wc = w & 1;
    const int l15 = lane & 15, l4 = lane >> 4;

    f32x4 acc[4][4] = {};

    for (int kt = 0; kt < 8; ++kt) {
        const int k0 = kt * 64;
        #pragma unroll
        for (int it = 0; it < 4; ++it) {
            const int seg = w * 4 + it;
            const int li = seg * 64 + lane;
            const int r = li >> 3;
            const int c8 = (li & 7) * 8;
            gload16(A + (size_t)(m0 + r) * DIM + k0 + c8, As + seg * 512);
            gload16(B + (size_t)(n0 + r) * DIM + k0 + c8, Bs + seg * 512);
        }
        asm volatile("s_waitcnt vmcnt(0)" ::: "memory");
        __syncthreads();
        #pragma unroll
        for (int kk = 0; kk < 2; ++kk) {
            short8 af[4], bfr[4];
            #pragma unroll
            for (int mf = 0; mf < 4; ++mf)
                af[mf] = *(const short8*)(As + (wr * 64 + mf * 16 + l15) * 64 + kk * 32 + l4 * 8);
            #pragma unroll
            for (int nf = 0; nf < 4; ++nf)
                bfr[nf] = *(const short8*)(Bs + (wc * 64 + nf * 16 + l15) * 64 + kk * 32 + l4 * 8);
            #pragma unroll
            for (int mf = 0; mf < 4; ++mf)
                #pragma unroll
                for (int nf = 0; nf < 4; ++nf)
                    acc[mf][nf] = __builtin_amdgcn_mfma_f32_16x16x32_bf16(af[mf], bfr[nf], acc[mf][nf], 0, 0, 0);
        }
        __syncthreads();
    }
    // epilogue: store bf16 S, fused column exp-sums (sink pass 1)
    if (tid < 128) cs[tid] = 0.f;
    __syncthreads();
    #pragma unroll
    for (int nf = 0; nf < 4; ++nf) {
        int col = n0 + wc * 64 + nf * 16 + l15;
        float csum = 0.f;
        if (col < NPROT) {
            #pragma unroll
            for (int mf = 0; mf < 4; ++mf)
                #pragma unroll
                for (int q = 0; q < 4; ++q) {
                    int row = m0 + wr * 64 + mf * 16 + l4 * 4 + q;
                    unsigned short sb = f2b(acc[mf][nf][q]);
                    C[(size_t)row * SLD + col] = sb;
                    csum += __expf(b2f(sb) * 20.0f);
                }
        }
        csum += __shfl_xor(csum, 16);
        csum += __shfl_xor(csum, 32);
        if (l4 == 0 && col < NPROT)
            atomicAdd(&cs[wc * 64 + nf * 16 + l15], csum);
    }
    __syncthreads();
    if (tid < 128) {
        int col = n0 + tid;
        if (col < NPROT) atomicAdd(&u1[col], cs[tid]);
    }
}

// ---------------- Sinkhorn pass (needs u_prev): u_out[k] += E * beta[n] ----------------
__global__ __launch_bounds__(512) void k_sink(const ushort_t* __restrict__ S,
                                              const float* __restrict__ u_prev,
                                              float* __restrict__ u_out) {
    __shared__ float part[8 * 512];
    const int tid = threadIdx.x;
    const int w = tid >> 6, lane = tid & 63;
    const bool lv = lane < 50;
    float rk[8];
    if (lv) {
        f32x4 u0 = *(const f32x4*)(u_prev + lane * 8);
        f32x4 u1 = *(const f32x4*)(u_prev + lane * 8 + 4);
        #pragma unroll
        for (int j = 0; j < 4; ++j) {
            rk[j] = 1.0f / (400.0f * u0[j]);
            rk[4 + j] = 1.0f / (400.0f * u1[j]);
        }
    } else {
        #pragma unroll
        for (int j = 0; j < 8; ++j) rk[j] = 0.0f;
    }
    float racc[8] = {0, 0, 0, 0, 0, 0, 0, 0};
    for (int row = blockIdx.x * 8 + w; row < N_SAMP; row += gridDim.x * 8) {
        short8 v = *(const short8*)(S + (size_t)row * SLD + lane * 8);
        float e[8];
        #pragma unroll
        for (int j = 0; j < 8; ++j)
            e[j] = lv ? __expf(b2f((unsigned short)v[j]) * 20.0f) : 0.0f;
        float t = 0.f;
        #pragma unroll
        for (int j = 0; j < 8; ++j) t += e[j] * rk[j];
        t = wred(t);
        float cn = 1.0f / ((float)N_SAMP * t);
        #pragma unroll
        for (int j = 0; j < 8; ++j) racc[j] += e[j] * cn;
    }
    #pragma unroll
    for (int j = 0; j < 8; ++j) part[w * 512 + lane * 8 + j] = racc[j];
    __syncthreads();
    float s = 0.f;
    #pragma unroll
    for (int w2 = 0; w2 < 8; ++w2) s += part[w2 * 512 + tid];
    if (tid < NPROT) atomicAdd(&u_out[tid], s);
}

// ---------------- phase A finalize: per-sample masked row-normalized weights ----------------
__global__ __launch_bounds__(512) void k_wprime(const ushort_t* __restrict__ S,
                                                const float* __restrict__ u3,
                                                const int* __restrict__ labels,
                                                float* __restrict__ w4) {
    const int tid = threadIdx.x;
    const int w = tid >> 6, lane = tid & 63;
    const int row = blockIdx.x * 8 + w;
    if (row >= N_SAMP) return;
    const bool lv = lane < 50;
    const int lab = labels[row];
    short8 v = *(const short8*)(S + (size_t)row * SLD + lane * 8);
    float contrib = 0.f, myval = 0.f;
    int myp = -1;
    if (lv) {
        f32x4 u0 = *(const f32x4*)(u3 + lane * 8);
        f32x4 u1 = *(const f32x4*)(u3 + lane * 8 + 4);
        #pragma unroll
        for (int j = 0; j < 8; ++j) {
            int k = lane * 8 + j;
            float uu = (j < 4) ? u0[j] : u1[j - 4];
            float r = 1.0f / (400.0f * uu);
            float e = __expf(b2f((unsigned short)v[j]) * 20.0f);
            int cls = k % 100;
            if (cls == lab) { float val = e * r; contrib += val; myval = val; myp = k / 100; }
        }
    }
    float Sn = wred(contrib);
    if (myp >= 0) w4[(size_t)row * 4 + myp] = myval / Sn;
}

// ---------------- class-bucketed gather (parallel over sample-chunks) ----------------
__global__ __launch_bounds__(128) void k_gather(const int* __restrict__ offsets,
                                                const int* __restrict__ idxlist,
                                                const float* __restrict__ w4,
                                                const ushort_t* __restrict__ fb,
                                                float* __restrict__ uf,
                                                float* __restrict__ colw) {
    const int c  = blockIdx.x / (4 * GCHUNK);
    const int rr = blockIdx.x % (4 * GCHUNK);
    const int dc = rr / GCHUNK;
    const int sc = rr % GCHUNK;
    const int d = dc * 128 + threadIdx.x;
    const int s = offsets[c], e = offsets[c + 1];
    const int cnt = e - s;
    const int per = (cnt + GCHUNK - 1) / GCHUNK;
    const int i0 = s + sc * per;
    const int i1 = min(e, i0 + per);
    if (i0 >= i1) return;
    float a0 = 0, a1 = 0, a2 = 0, a3 = 0, s0 = 0, s1 = 0, s2 = 0, s3 = 0;
    for (int i = i0; i < i1; ++i) {
        int n = idxlist[i];
        f32x4 wv = *(const f32x4*)(w4 + (size_t)n * 4);
        float f = b2f(fb[(size_t)n * DIM + d]);
        a0 += wv[0] * f; a1 += wv[1] * f; a2 += wv[2] * f; a3 += wv[3] * f;
        s0 += wv[0]; s1 += wv[1]; s2 += wv[2]; s3 += wv[3];
    }
    atomicAdd(&uf[(size_t)(c)       * DIM + d], a0);
    atomicAdd(&uf[(size_t)(c + 100) * DIM + d], a1);
    atomicAdd(&uf[(size_t)(c + 200) * DIM + d], a2);
    atomicAdd(&uf[(size_t)(c + 300) * DIM + d], a3);
    if (dc == 0 && threadIdx.x == 0) {
        atomicAdd(&colw[c], s0);
        atomicAdd(&colw[c + 100], s1);
        atomicAdd(&colw[c + 200], s2);
        atomicAdd(&colw[c + 300], s3);
    }
}

// ---------------- EMA + renorm ----------------
__global__ __launch_bounds__(64) void k_protonew(const float* __restrict__ protos,
                                                 const float* __restrict__ uf,
                                                 const float* __restrict__ colw,
                                                 float* __restrict__ pn,
                                                 ushort_t* __restrict__ pb) {
    const int k = blockIdx.x;
    const int lane = threadIdx.x;
    const float cw = fmaxf(colw[k], 1e-12f);
    float v[8]; float nn = 0.f;
    #pragma unroll
    for (int j = 0; j < 8; ++j) {
        int d = lane * 8 + j;
        float xx = 0.99f * protos[(size_t)k * DIM + d] + 0.01f * (uf[(size_t)k * DIM + d] / cw);
        v[j] = xx; nn += xx * xx;
    }
    nn = wred(nn);
    float inv = 1.0f / fmaxf(sqrtf(nn), 1e-12f);
    #pragma unroll
    for (int j = 0; j < 8; ++j) {
        int d = lane * 8 + j;
        float xx = v[j] * inv;
        pn[(size_t)k * DIM + d] = xx;
        pb[(size_t)k * DIM + d] = f2b(xx);
    }
}

// ---------------- proto-contrast ----------------
__global__ __launch_bounds__(256) void k_pcon(const float* __restrict__ pn, float* __restrict__ pacc) {
    __shared__ float pi[512];
    __shared__ float g[NPROT];
    __shared__ float rmx[4], rse[4], rsp[4];
    const int i = blockIdx.x;
    const int tid = threadIdx.x;
    const int w = tid >> 6, lane = tid & 63;
    for (int d = tid; d < 512; d += 256) pi[d] = pn[(size_t)i * DIM + d];
    __syncthreads();
    for (int j = w; j < NPROT; j += 4) {
        const float* pj = pn + (size_t)j * DIM;
        f32x4 p0 = *(const f32x4*)(pj + lane * 8);
        f32x4 p1 = *(const f32x4*)(pj + lane * 8 + 4);
        float dot = 0.f;
        #pragma unroll
        for (int jj = 0; jj < 4; ++jj) {
            dot += pi[lane * 8 + jj] * p0[jj];
            dot += pi[lane * 8 + 4 + jj] * p1[jj];
        }
        dot = wred(dot);
        if (lane == 0) g[j] = dot * 2.0f;
    }
    __syncthreads();
    float mx = -1e30f;
    for (int j = tid; j < NPROT; j += 256) mx = fmaxf(mx, g[j]);
    mx = wmax(mx);
    if (lane == 0) rmx[w] = mx;
    __syncthreads();
    mx = fmaxf(fmaxf(rmx[0], rmx[1]), fmaxf(rmx[2], rmx[3]));
    const int ci = i % 100;
    float se = 0.f, sp = 0.f;
    for (int j = tid; j < NPROT; j += 256) {
        if (j == i) continue;
        float lg = g[j] - mx;
        se += __expf(lg);
        if (j % 100 == ci) sp += lg;
    }
    se = wred(se); sp = wred(sp);
    if (lane == 0) { rse[w] = se; rsp[w] = sp; }
    __syncthreads();
    if (tid == 0) {
        float SE = rse[0] + rse[1] + rse[2] + rse[3];
        float SP = rsp[0] + rsp[1] + rsp[2] + rsp[3];
        atomicAdd(pacc, SP * (1.0f / 3.0f) - logf(SE));
    }
}

// ---------------- phase B finalize ----------------
__global__ __launch_bounds__(512) void k_final(const ushort_t* __restrict__ S,
                                               const float* __restrict__ u3,
                                               const int* __restrict__ labels,
                                               const float* __restrict__ pacc,
                                               float* __restrict__ out) {
    const int tid = threadIdx.x;
    const int w = tid >> 6, lane = tid & 63;
    const int row = blockIdx.x * 8 + w;
    if (row >= N_SAMP) return;
    const bool lv = lane < 50;
    const int lab = labels[row];
    short8 v = *(const short8*)(S + (size_t)row * SLD + lane * 8);
    float sw = 0.f, swl = 0.f, sexp = 0.f;
    if (lv) {
        f32x4 u0 = *(const f32x4*)(u3 + lane * 8);
        f32x4 u1 = *(const f32x4*)(u3 + lane * 8 + 4);
        #pragma unroll
        for (int j = 0; j < 8; ++j) {
            int k = lane * 8 + j;
            float s = b2f((unsigned short)v[j]);
            float e = __expf(s * 20.0f);
            float uu = (j < 4) ? u0[j] : u1[j - 4];
            float r = 1.0f / (400.0f * uu);
            float lgt = s * 10.0f;
            sexp += sqrtf(e);
            int cls = k % 100;
            if (cls == lab) { sw += e * r; swl += e * r * lgt; }
        }
    }
    sw = wred(sw); swl = wred(swl); sexp = wred(sexp);
    if (lane == 0) {
        float pos = swl / sw;
        float neg = logf(sexp);
        out[row] = (neg - pos) - pacc[0] * (1.0f / 400.0f);
    }
}

extern "C" void kernel_launch(void* const* d_in, const int* in_sizes, int n_in,
                              void* d_out, int out_size, void* d_ws, size_t ws_size,
                              hipStream_t stream) {
    const float* features = (const float*)d_in[0];
    const float* protos   = (const float*)d_in[1];
    const int*   labels   = (const int*)d_in[2];
    float* out = (float*)d_out;

    char* ws = (char*)d_ws;
    size_t off = 0;
    auto alloc = [&](size_t bytes) -> char* {
        char* p = ws + off;
        off += (bytes + 255) & ~(size_t)255;
        return p;
    };
    ushort_t* fbf16 = (ushort_t*)alloc((size_t)MPAD * DIM * 2);
    ushort_t* Sbuf  = (ushort_t*)alloc((size_t)MPAD * SLD * 2);
    ushort_t* pbf16 = (ushort_t*)alloc((size_t)DIM * DIM * 2);
    float* w4   = (float*)alloc((size_t)N_SAMP * 4 * 4);
    float* pnf  = (float*)alloc((size_t)NPROT * DIM * 4);
    float* zreg = (float*)alloc(16384);                  // zeroed region (contiguous with uf)
    float* uf   = (float*)alloc((size_t)NPROT * DIM * 4); // zeroed with zreg (one memset)
    float* uA1 = zreg;          float* uA2 = zreg + 512;  float* uA3 = zreg + 1024;
    float* uB1 = zreg + 1536;   float* uB2 = zreg + 2048; float* uB3 = zreg + 2560;
    float* pacc = zreg + 3072;
    int* counts = (int*)(zreg + 3080);
    float* colw = zreg + 3200;
    int* offsets = (int*)alloc(101 * 4);
    int* cursor  = (int*)alloc(100 * 4);
    int* idxlist = (int*)alloc((size_t)N_SAMP * 4);
    if (off > ws_size) return;

    // one memset covers zreg (16 KB) + uf (800 KB), they are adjacent
    hipMemsetAsync(zreg, 0, 16384 + (size_t)NPROT * DIM * 4, stream);

    k_prep<<<25216, 256, 0, stream>>>(features, protos, labels, fbf16, pbf16, counts);
    k_scan<<<1, 128, 0, stream>>>(counts, offsets, cursor);
    k_scatter<<<(N_SAMP + 255) / 256, 256, 0, stream>>>(labels, cursor, idxlist);

    const int GGRID = 8 * ((MB_CNT + 7) / 8) * 4;   // 3136, XCD-swizzled

    // ---- phase A ----
    k_gemm<<<GGRID, 256, 0, stream>>>(fbf16, pbf16, Sbuf, uA1);
    k_sink<<<512, 512, 0, stream>>>(Sbuf, uA1, uA2);
    k_sink<<<512, 512, 0, stream>>>(Sbuf, uA2, uA3);
    k_wprime<<<12500, 512, 0, stream>>>(Sbuf, uA3, labels, w4);
    k_gather<<<NCLS * 4 * GCHUNK, 128, 0, stream>>>(offsets, idxlist, w4, fbf16, uf, colw);
    k_protonew<<<400, 64, 0, stream>>>(protos, uf, colw, pnf, pbf16);
    k_pcon<<<400, 256, 0, stream>>>(pnf, pacc);

    // ---- phase B ----
    k_gemm<<<GGRID, 256, 0, stream>>>(fbf16, pbf16, Sbuf, uB1);
    k_sink<<<512, 512, 0, stream>>>(Sbuf, uB1, uB2);
    k_sink<<<512, 512, 0, stream>>>(Sbuf, uB2, uB3);
    k_final<<<12500, 512, 0, stream>>>(Sbuf, uB3, labels, pacc, out);
}

// Round 4
// 854.169 us; speedup vs baseline: 1.4277x; 1.0488x over previous
//
#include <hip/hip_runtime.h>
#include <hip/hip_bf16.h>

#define N_SAMP 100000
#define MPAD   100096   // 782*128
#define DIM    512
#define NCLS   100
#define NPROT  400
#define SLD    400      // S row stride (bf16 elements); 800 B rows, 16B-aligned
#define GCHUNK 16       // sample-chunks per class in gather
#define MB_CNT 782      // MPAD/128

typedef unsigned short ushort_t;
typedef __attribute__((ext_vector_type(8))) short short8;
typedef __attribute__((ext_vector_type(8))) unsigned short ushort8;
typedef __attribute__((ext_vector_type(4))) float f32x4;

__device__ __forceinline__ float b2f(unsigned short u) {
    unsigned int x = ((unsigned int)u) << 16;
    return __builtin_bit_cast(float, x);
}
__device__ __forceinline__ unsigned short f2b(float f) {
    unsigned int x = __builtin_bit_cast(unsigned int, f);
    unsigned int lsb = (x >> 16) & 1u;
    x += 0x7fffu + lsb;
    return (unsigned short)(x >> 16);
}
__device__ __forceinline__ float wred(float v) {
    #pragma unroll
    for (int m = 1; m < 64; m <<= 1) v += __shfl_xor(v, m);
    return v;
}
__device__ __forceinline__ float wmax(float v) {
    #pragma unroll
    for (int m = 1; m < 64; m <<= 1) v = fmaxf(v, __shfl_xor(v, m));
    return v;
}
__device__ __forceinline__ void gload16(const void* g, void* l) {
    __builtin_amdgcn_global_load_lds((const __attribute__((address_space(1))) void*)g,
                                     (__attribute__((address_space(3))) void*)l, 16, 0, 0);
}

// ---------------- fused prep: cvt feat + cvt protos + label count ----------------
__global__ void k_prep(const float* __restrict__ f, const float* __restrict__ p,
                       const int* __restrict__ labels,
                       ushort_t* __restrict__ fb, ushort_t* __restrict__ pb,
                       int* __restrict__ counts) {
    __shared__ int h[NCLS];
    const int b = blockIdx.x;
    if (b < 25024) {
        size_t idx = ((size_t)b * 256 + threadIdx.x) * 8;
        ushort8 r = {0,0,0,0,0,0,0,0};
        if (idx < (size_t)N_SAMP * DIM) {
            f32x4 a = *(const f32x4*)(f + idx);
            f32x4 c = *(const f32x4*)(f + idx + 4);
            #pragma unroll
            for (int j = 0; j < 4; ++j) { r[j] = f2b(a[j]); r[4 + j] = f2b(c[j]); }
        }
        *(ushort8*)(fb + idx) = r;
    } else if (b < 25152) {
        size_t idx = ((size_t)(b - 25024) * 256 + threadIdx.x) * 8;
        ushort8 r = {0,0,0,0,0,0,0,0};
        if (idx < (size_t)NPROT * DIM) {
            f32x4 a = *(const f32x4*)(p + idx);
            f32x4 c = *(const f32x4*)(p + idx + 4);
            #pragma unroll
            for (int j = 0; j < 4; ++j) { r[j] = f2b(a[j]); r[4 + j] = f2b(c[j]); }
        }
        *(ushort8*)(pb + idx) = r;
    } else {
        for (int i = threadIdx.x; i < NCLS; i += 256) h[i] = 0;
        __syncthreads();
        const int step = 64 * 256;
        for (int n = (b - 25152) * 256 + threadIdx.x; n < N_SAMP; n += step)
            atomicAdd(&h[labels[n]], 1);
        __syncthreads();
        for (int i = threadIdx.x; i < NCLS; i += 256)
            if (h[i]) atomicAdd(&counts[i], h[i]);
    }
}

// ---------------- parallel prefix scan over 100 class counts ----------------
__global__ void k_scan(const int* __restrict__ counts, int* __restrict__ offsets,
                       int* __restrict__ cursor) {
    __shared__ int c[NCLS];
    const int t = threadIdx.x;
    if (t < NCLS) c[t] = counts[t];
    __syncthreads();
    if (t <= NCLS) {
        int acc = 0;
        for (int i = 0; i < t && i < NCLS; ++i) acc += c[i];
        offsets[t] = acc;
        if (t < NCLS) cursor[t] = acc;
    }
}

__global__ void k_scatter(const int* __restrict__ labels, int* __restrict__ cursor,
                          int* __restrict__ idxlist) {
    int n = blockIdx.x * blockDim.x + threadIdx.x;
    if (n < N_SAMP) {
        int p = atomicAdd(&cursor[labels[n]], 1);
        idxlist[p] = n;
    }
}

// ---------------- GEMM + fused sink pass 1 ----------------
// C[MPAD,400(+pad)] = A[MPAD,512] @ B[512,512]^T, bf16; u1[k] += sum_rows exp(C*20)
// XCD-swizzled grid; double-buffered LDS pipeline with counted vmcnt;
// st-style XOR swizzle (linear LDS dest + pre-swizzled global source + swizzled ds_read).
__global__ __launch_bounds__(256) void k_gemm(const ushort_t* __restrict__ A,
                                              const ushort_t* __restrict__ B,
                                              ushort_t* __restrict__ C,
                                              float* __restrict__ u1) {
    __shared__ ushort_t As[2][128 * 64];
    __shared__ ushort_t Bs[2][128 * 64];
    __shared__ float cs[128];
    const int pidx = blockIdx.x;
    const int x = pidx & 7, sl = pidx >> 3;
    const int mb = (sl >> 2) * 8 + x;
    const int nb = sl & 3;
    if (mb >= MB_CNT) return;        // uniform early-out, before any barrier
    const int m0 = mb * 128, n0 = nb * 128;
    const int tid = threadIdx.x;
    const int w = tid >> 6, lane = tid & 63;
    const int wr = w >> 1, wc = w & 1;
    const int l15 = lane & 15, l4 = lane >> 4;
    const int swr = l15 & 7;          // row&7 for this lane's fragment rows

    f32x4 acc[4][4] = {};

    // stage K-tile kt into buffer buf. LDS slot (row r, col16 c) <- global colblock c^(r&7).
    auto stage = [&](int buf, int kt) {
        const int k0 = kt * 64;
        #pragma unroll
        for (int it = 0; it < 4; ++it) {
            const int seg = w * 4 + it;
            const int li = seg * 64 + lane;
            const int r = li >> 3;
            const int c8 = (((li & 7) ^ ((li >> 3) & 7))) * 8;   // pre-swizzled source colblock
            gload16(A + (size_t)(m0 + r) * DIM + k0 + c8, &As[buf][seg * 512]);
            gload16(B + (size_t)(n0 + r) * DIM + k0 + c8, &Bs[buf][seg * 512]);
        }
    };

    stage(0, 0);
    int cur = 0;
    #pragma unroll
    for (int kt = 0; kt < 8; ++kt) {
        if (kt < 7) {
            stage(cur ^ 1, kt + 1);
            asm volatile("s_waitcnt vmcnt(8)" ::: "memory");   // cur's 8 loads done; next's 8 in flight
        } else {
            asm volatile("s_waitcnt vmcnt(0)" ::: "memory");
        }
        __syncthreads();
        #pragma unroll
        for (int kk = 0; kk < 2; ++kk) {
            short8 af[4], bfr[4];
            #pragma unroll
            for (int mf = 0; mf < 4; ++mf)
                af[mf] = *(const short8*)(&As[cur][(wr * 64 + mf * 16 + l15) * 64 +
                                                   (((kk * 4 + l4) ^ swr)) * 8]);
            #pragma unroll
            for (int nf = 0; nf < 4; ++nf)
                bfr[nf] = *(const short8*)(&Bs[cur][(wc * 64 + nf * 16 + l15) * 64 +
                                                    (((kk * 4 + l4) ^ swr)) * 8]);
            #pragma unroll
            for (int mf = 0; mf < 4; ++mf)
                #pragma unroll
                for (int nf = 0; nf < 4; ++nf)
                    acc[mf][nf] = __builtin_amdgcn_mfma_f32_16x16x32_bf16(af[mf], bfr[nf], acc[mf][nf], 0, 0, 0);
        }
        __syncthreads();   // all reads of buf[cur] done before kt+1 issues writes into it
        cur ^= 1;
    }
    // epilogue: store bf16 S, fused column exp-sums (sink pass 1)
    if (tid < 128) cs[tid] = 0.f;
    __syncthreads();
    #pragma unroll
    for (int nf = 0; nf < 4; ++nf) {
        int col = n0 + wc * 64 + nf * 16 + l15;
        float csum = 0.f;
        if (col < NPROT) {
            #pragma unroll
            for (int mf = 0; mf < 4; ++mf)
                #pragma unroll
                for (int q = 0; q < 4; ++q) {
                    int row = m0 + wr * 64 + mf * 16 + l4 * 4 + q;
                    unsigned short sb = f2b(acc[mf][nf][q]);
                    C[(size_t)row * SLD + col] = sb;
                    csum += __expf(b2f(sb) * 20.0f);
                }
        }
        csum += __shfl_xor(csum, 16);
        csum += __shfl_xor(csum, 32);
        if (l4 == 0 && col < NPROT)
            atomicAdd(&cs[wc * 64 + nf * 16 + l15], csum);
    }
    __syncthreads();
    if (tid < 128) {
        int col = n0 + tid;
        if (col < NPROT) atomicAdd(&u1[col], cs[tid]);
    }
}

// ---------------- Sinkhorn pass (needs u_prev): u_out[k] += E * beta[n] ----------------
__global__ __launch_bounds__(512) void k_sink(const ushort_t* __restrict__ S,
                                              const float* __restrict__ u_prev,
                                              float* __restrict__ u_out) {
    __shared__ float part[8 * 512];
    const int tid = threadIdx.x;
    const int w = tid >> 6, lane = tid & 63;
    const bool lv = lane < 50;
    float rk[8];
    if (lv) {
        f32x4 u0 = *(const f32x4*)(u_prev + lane * 8);
        f32x4 u1 = *(const f32x4*)(u_prev + lane * 8 + 4);
        #pragma unroll
        for (int j = 0; j < 4; ++j) {
            rk[j] = 1.0f / (400.0f * u0[j]);
            rk[4 + j] = 1.0f / (400.0f * u1[j]);
        }
    } else {
        #pragma unroll
        for (int j = 0; j < 8; ++j) rk[j] = 0.0f;
    }
    float racc[8] = {0, 0, 0, 0, 0, 0, 0, 0};
    for (int row = blockIdx.x * 8 + w; row < N_SAMP; row += gridDim.x * 8) {
        short8 v = *(const short8*)(S + (size_t)row * SLD + lane * 8);
        float e[8];
        #pragma unroll
        for (int j = 0; j < 8; ++j)
            e[j] = lv ? __expf(b2f((unsigned short)v[j]) * 20.0f) : 0.0f;
        float t = 0.f;
        #pragma unroll
        for (int j = 0; j < 8; ++j) t += e[j] * rk[j];
        t = wred(t);
        float cn = 1.0f / ((float)N_SAMP * t);
        #pragma unroll
        for (int j = 0; j < 8; ++j) racc[j] += e[j] * cn;
    }
    #pragma unroll
    for (int j = 0; j < 8; ++j) part[w * 512 + lane * 8 + j] = racc[j];
    __syncthreads();
    float s = 0.f;
    #pragma unroll
    for (int w2 = 0; w2 < 8; ++w2) s += part[w2 * 512 + tid];
    if (tid < NPROT) atomicAdd(&u_out[tid], s);
}

// ---------------- phase A finalize: per-sample masked row-normalized weights ----------------
__global__ __launch_bounds__(512) void k_wprime(const ushort_t* __restrict__ S,
                                                const float* __restrict__ u3,
                                                const int* __restrict__ labels,
                                                float* __restrict__ w4) {
    const int tid = threadIdx.x;
    const int w = tid >> 6, lane = tid & 63;
    const int row = blockIdx.x * 8 + w;
    if (row >= N_SAMP) return;
    const bool lv = lane < 50;
    const int lab = labels[row];
    short8 v = *(const short8*)(S + (size_t)row * SLD + lane * 8);
    float contrib = 0.f, myval = 0.f;
    int myp = -1;
    if (lv) {
        f32x4 u0 = *(const f32x4*)(u3 + lane * 8);
        f32x4 u1 = *(const f32x4*)(u3 + lane * 8 + 4);
        #pragma unroll
        for (int j = 0; j < 8; ++j) {
            int k = lane * 8 + j;
            float uu = (j < 4) ? u0[j] : u1[j - 4];
            float r = 1.0f / (400.0f * uu);
            float e = __expf(b2f((unsigned short)v[j]) * 20.0f);
            int cls = k % 100;
            if (cls == lab) { float val = e * r; contrib += val; myval = val; myp = k / 100; }
        }
    }
    float Sn = wred(contrib);
    if (myp >= 0) w4[(size_t)row * 4 + myp] = myval / Sn;
}

// ---------------- class-bucketed gather (parallel over sample-chunks) ----------------
__global__ __launch_bounds__(128) void k_gather(const int* __restrict__ offsets,
                                                const int* __restrict__ idxlist,
                                                const float* __restrict__ w4,
                                                const ushort_t* __restrict__ fb,
                                                float* __restrict__ uf,
                                                float* __restrict__ colw) {
    const int c  = blockIdx.x / (4 * GCHUNK);
    const int rr = blockIdx.x % (4 * GCHUNK);
    const int dc = rr / GCHUNK;
    const int sc = rr % GCHUNK;
    const int d = dc * 128 + threadIdx.x;
    const int s = offsets[c], e = offsets[c + 1];
    const int cnt = e - s;
    const int per = (cnt + GCHUNK - 1) / GCHUNK;
    const int i0 = s + sc * per;
    const int i1 = min(e, i0 + per);
    if (i0 >= i1) return;
    float a0 = 0, a1 = 0, a2 = 0, a3 = 0, s0 = 0, s1 = 0, s2 = 0, s3 = 0;
    for (int i = i0; i < i1; ++i) {
        int n = idxlist[i];
        f32x4 wv = *(const f32x4*)(w4 + (size_t)n * 4);
        float f = b2f(fb[(size_t)n * DIM + d]);
        a0 += wv[0] * f; a1 += wv[1] * f; a2 += wv[2] * f; a3 += wv[3] * f;
        s0 += wv[0]; s1 += wv[1]; s2 += wv[2]; s3 += wv[3];
    }
    atomicAdd(&uf[(size_t)(c)       * DIM + d], a0);
    atomicAdd(&uf[(size_t)(c + 100) * DIM + d], a1);
    atomicAdd(&uf[(size_t)(c + 200) * DIM + d], a2);
    atomicAdd(&uf[(size_t)(c + 300) * DIM + d], a3);
    if (dc == 0 && threadIdx.x == 0) {
        atomicAdd(&colw[c], s0);
        atomicAdd(&colw[c + 100], s1);
        atomicAdd(&colw[c + 200], s2);
        atomicAdd(&colw[c + 300], s3);
    }
}

// ---------------- EMA + renorm ----------------
__global__ __launch_bounds__(64) void k_protonew(const float* __restrict__ protos,
                                                 const float* __restrict__ uf,
                                                 const float* __restrict__ colw,
                                                 float* __restrict__ pn,
                                                 ushort_t* __restrict__ pb) {
    const int k = blockIdx.x;
    const int lane = threadIdx.x;
    const float cw = fmaxf(colw[k], 1e-12f);
    float v[8]; float nn = 0.f;
    #pragma unroll
    for (int j = 0; j < 8; ++j) {
        int d = lane * 8 + j;
        float xx = 0.99f * protos[(size_t)k * DIM + d] + 0.01f * (uf[(size_t)k * DIM + d] / cw);
        v[j] = xx; nn += xx * xx;
    }
    nn = wred(nn);
    float inv = 1.0f / fmaxf(sqrtf(nn), 1e-12f);
    #pragma unroll
    for (int j = 0; j < 8; ++j) {
        int d = lane * 8 + j;
        float xx = v[j] * inv;
        pn[(size_t)k * DIM + d] = xx;
        pb[(size_t)k * DIM + d] = f2b(xx);
    }
}

// ---------------- proto-contrast ----------------
__global__ __launch_bounds__(256) void k_pcon(const float* __restrict__ pn, float* __restrict__ pacc) {
    __shared__ float pi[512];
    __shared__ float g[NPROT];
    __shared__ float rmx[4], rse[4], rsp[4];
    const int i = blockIdx.x;
    const int tid = threadIdx.x;
    const int w = tid >> 6, lane = tid & 63;
    for (int d = tid; d < 512; d += 256) pi[d] = pn[(size_t)i * DIM + d];
    __syncthreads();
    for (int j = w; j < NPROT; j += 4) {
        const float* pj = pn + (size_t)j * DIM;
        f32x4 p0 = *(const f32x4*)(pj + lane * 8);
        f32x4 p1 = *(const f32x4*)(pj + lane * 8 + 4);
        float dot = 0.f;
        #pragma unroll
        for (int jj = 0; jj < 4; ++jj) {
            dot += pi[lane * 8 + jj] * p0[jj];
            dot += pi[lane * 8 + 4 + jj] * p1[jj];
        }
        dot = wred(dot);
        if (lane == 0) g[j] = dot * 2.0f;
    }
    __syncthreads();
    float mx = -1e30f;
    for (int j = tid; j < NPROT; j += 256) mx = fmaxf(mx, g[j]);
    mx = wmax(mx);
    if (lane == 0) rmx[w] = mx;
    __syncthreads();
    mx = fmaxf(fmaxf(rmx[0], rmx[1]), fmaxf(rmx[2], rmx[3]));
    const int ci = i % 100;
    float se = 0.f, sp = 0.f;
    for (int j = tid; j < NPROT; j += 256) {
        if (j == i) continue;
        float lg = g[j] - mx;
        se += __expf(lg);
        if (j % 100 == ci) sp += lg;
    }
    se = wred(se); sp = wred(sp);
    if (lane == 0) { rse[w] = se; rsp[w] = sp; }
    __syncthreads();
    if (tid == 0) {
        float SE = rse[0] + rse[1] + rse[2] + rse[3];
        float SP = rsp[0] + rsp[1] + rsp[2] + rsp[3];
        atomicAdd(pacc, SP * (1.0f / 3.0f) - logf(SE));
    }
}

// ---------------- phase B finalize ----------------
__global__ __launch_bounds__(512) void k_final(const ushort_t* __restrict__ S,
                                               const float* __restrict__ u3,
                                               const int* __restrict__ labels,
                                               const float* __restrict__ pacc,
                                               float* __restrict__ out) {
    const int tid = threadIdx.x;
    const int w = tid >> 6, lane = tid & 63;
    const int row = blockIdx.x * 8 + w;
    if (row >= N_SAMP) return;
    const bool lv = lane < 50;
    const int lab = labels[row];
    short8 v = *(const short8*)(S + (size_t)row * SLD + lane * 8);
    float sw = 0.f, swl = 0.f, sexp = 0.f;
    if (lv) {
        f32x4 u0 = *(const f32x4*)(u3 + lane * 8);
        f32x4 u1 = *(const f32x4*)(u3 + lane * 8 + 4);
        #pragma unroll
        for (int j = 0; j < 8; ++j) {
            int k = lane * 8 + j;
            float s = b2f((unsigned short)v[j]);
            float e = __expf(s * 20.0f);
            float uu = (j < 4) ? u0[j] : u1[j - 4];
            float r = 1.0f / (400.0f * uu);
            float lgt = s * 10.0f;
            sexp += sqrtf(e);
            int cls = k % 100;
            if (cls == lab) { sw += e * r; swl += e * r * lgt; }
        }
    }
    sw = wred(sw); swl = wred(swl); sexp = wred(sexp);
    if (lane == 0) {
        float pos = swl / sw;
        float neg = logf(sexp);
        out[row] = (neg - pos) - pacc[0] * (1.0f / 400.0f);
    }
}

extern "C" void kernel_launch(void* const* d_in, const int* in_sizes, int n_in,
                              void* d_out, int out_size, void* d_ws, size_t ws_size,
                              hipStream_t stream) {
    const float* features = (const float*)d_in[0];
    const float* protos   = (const float*)d_in[1];
    const int*   labels   = (const int*)d_in[2];
    float* out = (float*)d_out;

    char* ws = (char*)d_ws;
    size_t off = 0;
    auto alloc = [&](size_t bytes) -> char* {
        char* p = ws + off;
        off += (bytes + 255) & ~(size_t)255;
        return p;
    };
    ushort_t* fbf16 = (ushort_t*)alloc((size_t)MPAD * DIM * 2);
    ushort_t* Sbuf  = (ushort_t*)alloc((size_t)MPAD * SLD * 2);
    ushort_t* pbf16 = (ushort_t*)alloc((size_t)DIM * DIM * 2);
    float* w4   = (float*)alloc((size_t)N_SAMP * 4 * 4);
    float* pnf  = (float*)alloc((size_t)NPROT * DIM * 4);
    float* zreg = (float*)alloc(16384);                  // zeroed region (contiguous with uf)
    float* uf   = (float*)alloc((size_t)NPROT * DIM * 4); // zeroed with zreg (one memset)
    float* uA1 = zreg;          float* uA2 = zreg + 512;  float* uA3 = zreg + 1024;
    float* uB1 = zreg + 1536;   float* uB2 = zreg + 2048; float* uB3 = zreg + 2560;
    float* pacc = zreg + 3072;
    int* counts = (int*)(zreg + 3080);
    float* colw = zreg + 3200;
    int* offsets = (int*)alloc(101 * 4);
    int* cursor  = (int*)alloc(100 * 4);
    int* idxlist = (int*)alloc((size_t)N_SAMP * 4);
    if (off > ws_size) return;

    // one memset covers zreg (16 KB) + uf (800 KB), they are adjacent
    hipMemsetAsync(zreg, 0, 16384 + (size_t)NPROT * DIM * 4, stream);

    k_prep<<<25216, 256, 0, stream>>>(features, protos, labels, fbf16, pbf16, counts);
    k_scan<<<1, 128, 0, stream>>>(counts, offsets, cursor);
    k_scatter<<<(N_SAMP + 255) / 256, 256, 0, stream>>>(labels, cursor, idxlist);

    const int GGRID = 8 * ((MB_CNT + 7) / 8) * 4;   // 3136, XCD-swizzled

    // ---- phase A ----
    k_gemm<<<GGRID, 256, 0, stream>>>(fbf16, pbf16, Sbuf, uA1);
    k_sink<<<512, 512, 0, stream>>>(Sbuf, uA1, uA2);
    k_sink<<<512, 512, 0, stream>>>(Sbuf, uA2, uA3);
    k_wprime<<<12500, 512, 0, stream>>>(Sbuf, uA3, labels, w4);
    k_gather<<<NCLS * 4 * GCHUNK, 128, 0, stream>>>(offsets, idxlist, w4, fbf16, uf, colw);
    k_protonew<<<400, 64, 0, stream>>>(protos, uf, colw, pnf, pbf16);
    k_pcon<<<400, 256, 0, stream>>>(pnf, pacc);

    // ---- phase B ----
    k_gemm<<<GGRID, 256, 0, stream>>>(fbf16, pbf16, Sbuf, uB1);
    k_sink<<<512, 512, 0, stream>>>(Sbuf, uB1, uB2);
    k_sink<<<512, 512, 0, stream>>>(Sbuf, uB2, uB3);
    k_final<<<12500, 512, 0, stream>>>(Sbuf, uB3, labels, pacc, out);
}